// Round 5
// baseline (266.957 us; speedup 1.0000x reference)
//
#include <hip/hip_runtime.h>

// Problem constants: B=8, N=4096, DIM=C=512, E=8, K=2, H=16, T=B*N=32768
#define T_TOK 32768
#define C_DIM 512
#define N_SEQ 4096

typedef unsigned short ushort_t;
typedef unsigned int uint_t;
typedef __attribute__((ext_vector_type(8))) _Float16 half8;
typedef __attribute__((ext_vector_type(4))) float f32x4;

static __device__ __forceinline__ ushort_t f2h_bits(float f) {
  _Float16 h = (_Float16)f;
  return __builtin_bit_cast(ushort_t, h);
}
static __device__ __forceinline__ float h_bits2f(ushort_t u) {
  return (float)__builtin_bit_cast(_Float16, u);
}

// LDS tile: R rows x 32 f16 (64B rows), stored in 16B slots with XOR swizzle
// slot p holds logical (r = p>>2, q = (p&3) ^ ((r>>1)&3)). Fragment read for
// (row r, k-quarter q) -> ushort off r*32 + (q ^ ((r>>1)&3))*8 => 2-way (free)
// bank aliasing on ds_read_b128 instead of 8-way.
static __device__ __forceinline__ half8 frag_ld(const ushort_t* base, int r, int q) {
  const int off = r * 32 + ((q ^ ((r >> 1) & 3)) * 8);  // in ushorts
  return *(const half8*)(base + off);
}

#define GLOAD_LDS(gptr, lptr)                                                  \
  __builtin_amdgcn_global_load_lds(                                            \
      (const __attribute__((address_space(1))) uint_t*)(gptr),                 \
      (__attribute__((address_space(3))) uint_t*)(lptr), 16, 0, 0)

// ---------------------------------------------------------------------------
// prep (weights-only, grid 1024): wg1 -> hi/lo, w1 -> W1t, w2+b2 -> W2t;
// block 1023 zeroes stats+usage+done.
// ---------------------------------------------------------------------------
__global__ __launch_bounds__(256) void prep(
    const float* __restrict__ wg1, const float* __restrict__ w1,
    const float* __restrict__ w2, const float* __restrict__ b2,
    ushort_t* __restrict__ Whi, ushort_t* __restrict__ Wlo,
    ushort_t* __restrict__ W1t, ushort_t* __restrict__ W2t,
    float* __restrict__ stats, float* __restrict__ usage,
    uint_t* __restrict__ done) {
  const int idx = blockIdx.x * 256 + threadIdx.x;  // 0..262143
  {
    const float v = wg1[idx];
    const ushort_t h = f2h_bits(v);
    Whi[idx] = h;
    Wlo[idx] = f2h_bits(v - h_bits2f(h));
  }
  if (idx < 65536) {
    const int eh = idx >> 9, c = idx & 511;
    const int e = eh >> 4, hh = eh & 15;
    W1t[idx] = f2h_bits(w1[((size_t)e * 512 + c) * 16 + hh]);
  }
  if (idx < 81920) {
    const int c = idx / 160, k = idx - c * 160;
    float v = 0.f;
    if (k < 128) {
      const int e = k >> 4, hh = k & 15;
      v = w2[((size_t)e * 16 + hh) * 512 + c];
    } else if (k < 136) {
      v = b2[(size_t)(k - 128) * 512 + c];
    }
    W2t[c * 160 + k] = f2h_bits(v);
  }
  if (blockIdx.x == 1023) {
    float4 z = {0.f, 0.f, 0.f, 0.f};
    *(float4*)&stats[threadIdx.x * 4] = z;  // 1024 floats
    if (threadIdx.x < 8) usage[threadIdx.x] = 0.f;
    if (threadIdx.x == 8) *done = 0u;
  }
}

// ---------------------------------------------------------------------------
// K1: gate GEMM via split-f16 MFMA, h = (xhi+xlo)@(whi+wlo)^T + bg1.
// 1-D grid 1024; decode puts the 4 n-siblings of an m-strip 8 apart in
// linear ID -> same XCD (b%8) and near-simultaneous dispatch, so the X
// row-strip is fetched from HBM once per XCD-group instead of 4x.
// R5: 1-barrier dbuf pipeline. Per chunk: cvt(xr)->ds_write sA[cur];
// ONE barrier (drains B(kc) gloads issued a full compute phase ago + the
// A ds_writes); then issue X(kc+1)->regs and B(kc+1)->sB[cur^1]; then 48
// MFMAs. Loads are issued post-barrier, consumed post-NEXT-barrier, so the
// implicit vmcnt(0) at the barrier lands on ~complete loads (was: 2-barrier
// structure draining B immediately -> full L2 latency exposed 16x/block).
// X issued before B each iter so cvt's wait-for-X doesn't drain B prefetch.
// LDS 64KB (A,B hi/lo dbuf) -> 2 blocks/CU.
// ---------------------------------------------------------------------------
__global__ __launch_bounds__(256) void k1_mfma(
    const float* __restrict__ X, const ushort_t* __restrict__ Whi,
    const ushort_t* __restrict__ Wlo, const float* __restrict__ bg1,
    float* __restrict__ H, float* __restrict__ stats) {
  __shared__ ushort_t sAh[2][4096], sAl[2][4096];  // 32 KB
  __shared__ ushort_t sBh[2][4096], sBl[2][4096];  // 32 KB
  const int tid = threadIdx.x, lane = tid & 63, w = tid >> 6;
  const int wm = w >> 1, wn = w & 1;
  const int b = blockIdx.x;
  const int m0 = ((b & 7) | ((b >> 5) << 3)) * 128;  // b = 32*(m>>3)+8*n+(m&7)
  const int n0 = ((b >> 3) & 3) * 128;
  const int cl = lane & 15, qf = lane >> 4;

  // A-slot geometry: thread handles swizzled slots p1=tid, p2=tid+256
  // (slot p = 8 consecutive f16 of row r=p>>2, k-quarter q=(p&3)^((r>>1)&3)).
  const int p1 = tid, p2 = tid + 256;
  const int r1 = p1 >> 2, q1 = (p1 & 3) ^ ((r1 >> 1) & 3);
  const int r2 = p2 >> 2, q2 = (p2 & 3) ^ ((r2 >> 1) & 3);
  const float* xb1 = X + (size_t)(m0 + r1) * 512 + q1 * 8;
  const float* xb2 = X + (size_t)(m0 + r2) * 512 + q2 * 8;

  float4 xr[4];
#define K1_LOADX(kc)                                                           \
  {                                                                            \
    const int kk = (kc) * 32;                                                  \
    xr[0] = *(const float4*)(xb1 + kk);                                        \
    xr[1] = *(const float4*)(xb1 + kk + 4);                                    \
    xr[2] = *(const float4*)(xb2 + kk);                                        \
    xr[3] = *(const float4*)(xb2 + kk + 4);                                    \
  }

  // B staging: 512 slots/matrix/chunk; each thread issues 2 Whi + 2 Wlo.
#define K1_STAGEB(kc, buf)                                                     \
  {                                                                            \
    const int k0s = (kc) * 32;                                                 \
    _Pragma("unroll") for (int j = 0; j < 2; ++j) {                            \
      const int pb = (w * 2 + j) * 64 + lane;                                  \
      const int rb = pb >> 2, qb = (pb & 3) ^ ((rb >> 1) & 3);                 \
      GLOAD_LDS(Whi + (size_t)(n0 + rb) * 512 + k0s + qb * 8, sBh[buf] + pb * 8); \
      GLOAD_LDS(Wlo + (size_t)(n0 + rb) * 512 + k0s + qb * 8, sBl[buf] + pb * 8); \
    }                                                                          \
  }

  K1_LOADX(0);
  K1_STAGEB(0, 0);
  f32x4 acc[4][4] = {};

  for (int kc = 0; kc < 16; ++kc) {
    const int cur = kc & 1;
    // A conversion + swizzled ds_write (xr loaded a full compute phase ago)
    {
      ushort_t hi[16], lo[16];
      const float* v = (const float*)xr;
#pragma unroll
      for (int j = 0; j < 16; ++j) {
        hi[j] = f2h_bits(v[j]);
        lo[j] = f2h_bits(v[j] - h_bits2f(hi[j]));
      }
      *(uint4*)(sAh[cur] + p1 * 8) = *(uint4*)(hi);
      *(uint4*)(sAl[cur] + p1 * 8) = *(uint4*)(lo);
      *(uint4*)(sAh[cur] + p2 * 8) = *(uint4*)(hi + 8);
      *(uint4*)(sAl[cur] + p2 * 8) = *(uint4*)(lo + 8);
    }
    __syncthreads();  // drains B(kc) gloads (in flight ~1 compute phase) + A ds_writes
    if (kc < 15) {
      K1_LOADX(kc + 1);        // X first: cvt's wait-for-X won't drain B
      K1_STAGEB(kc + 1, cur ^ 1);
    }

    half8 ah[4], al[4], bh[4], bl[4];
#pragma unroll
    for (int f = 0; f < 4; ++f) {
      ah[f] = frag_ld(sAh[cur], wm * 64 + f * 16 + cl, qf);
      al[f] = frag_ld(sAl[cur], wm * 64 + f * 16 + cl, qf);
      bh[f] = frag_ld(sBh[cur], wn * 64 + f * 16 + cl, qf);
      bl[f] = frag_ld(sBl[cur], wn * 64 + f * 16 + cl, qf);
    }
#pragma unroll
    for (int i = 0; i < 4; ++i)
#pragma unroll
      for (int j = 0; j < 4; ++j) {
        acc[i][j] = __builtin_amdgcn_mfma_f32_16x16x32_f16(ah[i], bh[j], acc[i][j], 0, 0, 0);
        acc[i][j] = __builtin_amdgcn_mfma_f32_16x16x32_f16(ah[i], bl[j], acc[i][j], 0, 0, 0);
        acc[i][j] = __builtin_amdgcn_mfma_f32_16x16x32_f16(al[i], bh[j], acc[i][j], 0, 0, 0);
      }
  }
#undef K1_LOADX
#undef K1_STAGEB

  float s[4] = {0, 0, 0, 0}, qs[4] = {0, 0, 0, 0};
  const int rq = lane >> 4;
#pragma unroll
  for (int nf = 0; nf < 4; ++nf) {
    const int col = n0 + wn * 64 + nf * 16 + cl;
    const float bv = bg1[col];
#pragma unroll
    for (int mf = 0; mf < 4; ++mf) {
      const int row = m0 + wm * 64 + mf * 16 + rq * 4;
#pragma unroll
      for (int i = 0; i < 4; ++i) {
        const float v = acc[mf][nf][i] + bv;
        H[(size_t)(row + i) * 512 + col] = v;
        s[nf] += v;
        qs[nf] += v * v;
      }
    }
  }
#pragma unroll
  for (int nf = 0; nf < 4; ++nf) {
    s[nf] += __shfl_xor(s[nf], 16, 64);
    qs[nf] += __shfl_xor(qs[nf], 16, 64);
    s[nf] += __shfl_xor(s[nf], 32, 64);
    qs[nf] += __shfl_xor(qs[nf], 32, 64);
  }
  if (lane < 16) {
#pragma unroll
    for (int nf = 0; nf < 4; ++nf) {
      const int col = n0 + wn * 64 + nf * 16 + cl;
      atomicAdd(&stats[col], s[nf]);
      atomicAdd(&stats[512 + col], qs[nf]);
    }
  }
}

// ---------------------------------------------------------------------------
// K5 (fused gate+FC1+FC2), 64 tokens/block, grid 512 (2 blocks/CU, ~70KB LDS)
// -- R1 best-measured config (72us), FC1 A-path reads X fp32, converts hi
// in-register:
//   (a) BN finalize (recomputed) + gating top-2/softmax -> wtab + P ext cols
//   (b) FC1 MFMA (Xhi @ W1t^T): X->reg (issued at kernel start / during
//       previous chunk's MFMA) -> cvt -> ds_write into dbuf'd LDS tile;
//       ONE barrier per chunk. B (W1t, L1-hot slices) direct-to-register.
//   (c) FC2 MFMA (Pl @ W2t^T, K=160 incl b2 cols): Pl LDS-resident, B
//       direct-to-register -> zero k-loop barriers.
//   lb_loss by last-finisher ticket on `done` (512 blocks -> ticket 511).
// Pl width 168: A-frag stride 336B -> 2-way (free) LDS bank aliasing.
// NOTE uint4 = 8 f16 elements: ext-col zeroing [128,160) = 4 chunks of 8.
// ---------------------------------------------------------------------------
__global__ __launch_bounds__(256) void k5_fused(
    const float* __restrict__ X, const ushort_t* __restrict__ W1t,
    const ushort_t* __restrict__ W2t, const float* __restrict__ b1,
    const float* __restrict__ H, const float* __restrict__ stats,
    const float* __restrict__ gamma, const float* __restrict__ beta,
    const float* __restrict__ wg2, const float* __restrict__ bg2,
    float* __restrict__ usage, uint_t* __restrict__ done,
    float* __restrict__ Out) {
  __shared__ ushort_t sA[2][2048];      // 8 KB  (FC1 A dbuf, 64 rows x 32 k)
  __shared__ ushort_t Pl[64 * 168];     // 21.5 KB
  __shared__ float wtab[64 * 8];        // 2 KB
  __shared__ float ys[128 * 68];        // 34.8 KB
  __shared__ float scsh_l[1024];        // 4 KB
  __shared__ float lus[8];

  const int tid = threadIdx.x, lane = tid & 63, w = tid >> 6;
  const int wm = w >> 1, wn = w & 1;
  const int t0 = blockIdx.x * 64;
  const int bi = t0 >> 12, n0 = t0 & 4095;
  const int cl = lane & 15, qf = lane >> 4, rq = lane >> 4;

  // A-slot geometry (1 slot/thread: 64 rows x 4 slots) + chunk-0 issue NOW,
  // so the X load latency hides under the whole BN+gating phase.
  const int pA = tid, rA = pA >> 2, qA = (pA & 3) ^ ((rA >> 1) & 3);
  const float* xbase = X + (size_t)(t0 + rA) * 512 + qA * 8;
  float4 xq0 = *(const float4*)(xbase);
  float4 xq1 = *(const float4*)(xbase + 4);

  // ---- init: zero wtab, P ext cols [128,160); BN scale/shift --------------
  if (tid < 8) lus[tid] = 0.f;
  wtab[tid] = 0.f;
  wtab[tid + 256] = 0.f;
  {
    uint4 z = {0, 0, 0, 0};
    const int row = tid >> 2, hf = tid & 3;
    *(uint4*)&Pl[row * 168 + 128 + hf * 8] = z;  // cols 128..159
  }
#pragma unroll
  for (int rep = 0; rep < 2; ++rep) {
    const int c = tid + rep * 256;
    const double mu = (double)stats[c] * (1.0 / (double)T_TOK);
    const double var = (double)stats[512 + c] * (1.0 / (double)T_TOK) - mu * mu;
    const double rstd = 1.0 / sqrt(var + 1e-5);
    const float scv = (float)((double)gamma[c] * rstd);
    scsh_l[c] = scv;
    scsh_l[512 + c] = beta[c] - (float)mu * scv;
  }
  __syncthreads();

  // ---- (a) gating: 4 waves x 16 tokens ------------------------------------
  {
    const int cb = lane * 8;
    float sc[8], sh[8];
#pragma unroll
    for (int i = 0; i < 8; ++i) {
      sc[i] = scsh_l[cb + i];
      sh[i] = scsh_l[512 + cb + i];
    }
    float wg[8][8];
#pragma unroll
    for (int e = 0; e < 8; ++e)
#pragma unroll
      for (int i = 0; i < 8; ++i) wg[e][i] = wg2[e * C_DIM + cb + i];
    float bg[8];
#pragma unroll
    for (int e = 0; e < 8; ++e) bg[e] = bg2[e];

#pragma unroll 2
    for (int it = 0; it < 16; ++it) {
      const int tl = w * 16 + it;
      const float* hr = H + (size_t)(t0 + tl) * C_DIM + cb;
      float4 h0 = *(const float4*)hr;
      float4 h1 = *(const float4*)(hr + 4);
      float y[8] = {h0.x, h0.y, h0.z, h0.w, h1.x, h1.y, h1.z, h1.w};
#pragma unroll
      for (int i = 0; i < 8; ++i) y[i] = fmaxf(fmaf(y[i], sc[i], sh[i]), 0.f);

      float lg[8];
#pragma unroll
      for (int e = 0; e < 8; ++e) {
        float sum = 0.f;
#pragma unroll
        for (int i = 0; i < 8; ++i) sum = fmaf(y[i], wg[e][i], sum);
        lg[e] = sum;
      }
#pragma unroll
      for (int d = 1; d < 64; d <<= 1)
#pragma unroll
        for (int e = 0; e < 8; ++e) lg[e] += __shfl_xor(lg[e], d, 64);
#pragma unroll
      for (int e = 0; e < 8; ++e) lg[e] += bg[e];

      float v1 = lg[0]; int i1 = 0;
#pragma unroll
      for (int e = 1; e < 8; ++e)
        if (lg[e] > v1) { v1 = lg[e]; i1 = e; }
      float v2 = -3.4e38f; int i2 = 0;
#pragma unroll
      for (int e = 0; e < 8; ++e)
        if (e != i1 && lg[e] > v2) { v2 = lg[e]; i2 = e; }

      const float p = expf(v2 - v1);
      const float rw = 1.f / (1.f + p);
      const float w0 = rw, w1 = p * rw;

      if (lane == 0) {
        wtab[tl * 8 + i1] = w0;
        wtab[tl * 8 + i2] = w1;
        Pl[tl * 168 + 128 + i1] = f2h_bits(w0);
        Pl[tl * 168 + 128 + i2] = f2h_bits(w1);
        atomicAdd(&lus[i1], w0);
        atomicAdd(&lus[i2], w1);
      }
    }
  }
  __syncthreads();
  if (tid < 8) atomicAdd(&usage[tid], lus[tid]);
  __syncthreads();
  if (tid == 0) {
    __threadfence();
    const uint_t ticket = atomicAdd(done, 1u);
    if (ticket == 511u) {
      float s = 0.f;
#pragma unroll
      for (int e = 0; e < 8; ++e) {
        const float u = atomicAdd(&usage[e], 0.f) * (1.f / (float)T_TOK);
        s += u * u;
      }
      Out[(size_t)16777216] = s * 8.f;
    }
  }

  // ---- (b) FC1: [64 tok x 128 eh] = Xhi @ W1t^T ---------------------------
  // X->reg (dbuf) -> cvt hi -> ds_write sA[kc&1]; one barrier per chunk;
  // B frags direct from global (L1-hot slices).
  f32x4 acc[2][4] = {};
  for (int kc = 0; kc < 16; ++kc) {
    const int k0 = kc * 32;
    {
      ushort_t hi[8];
      const float v[8] = {xq0.x, xq0.y, xq0.z, xq0.w, xq1.x, xq1.y, xq1.z, xq1.w};
#pragma unroll
      for (int j = 0; j < 8; ++j) hi[j] = f2h_bits(v[j]);
      *(uint4*)(sA[kc & 1] + pA * 8) = *(uint4*)hi;
    }
    __syncthreads();  // ds_writes visible; dbuf makes WAR safe w/ one barrier
    if (kc < 15) {
      xq0 = *(const float4*)(xbase + k0 + 32);
      xq1 = *(const float4*)(xbase + k0 + 36);
    }
    half8 bf[4];
#pragma unroll
    for (int f = 0; f < 4; ++f)
      bf[f] = *(const half8*)(W1t + (size_t)(wn * 64 + f * 16 + cl) * 512 + k0 + qf * 8);
    half8 af[2];
#pragma unroll
    for (int f = 0; f < 2; ++f) af[f] = frag_ld(sA[kc & 1], wm * 32 + f * 16 + cl, qf);
#pragma unroll
    for (int i = 0; i < 2; ++i)
#pragma unroll
      for (int j = 0; j < 4; ++j)
        acc[i][j] = __builtin_amdgcn_mfma_f32_16x16x32_f16(af[i], bf[j], acc[i][j], 0, 0, 0);
  }

  // FC1 epilogue: bias, relu, gate-weight -> Pl (e is wave-uniform per nf)
  {
#pragma unroll
    for (int nf = 0; nf < 4; ++nf) {
      const int col = wn * 64 + nf * 16 + cl;
      const float bv = b1[col];
      const int e = wn * 4 + nf;  // col>>4
#pragma unroll
      for (int mf = 0; mf < 2; ++mf) {
        const int row = wm * 32 + mf * 16 + rq * 4;
#pragma unroll
        for (int i = 0; i < 4; ++i) {
          const float v = fmaxf(acc[mf][nf][i] + bv, 0.f) * wtab[(row + i) * 8 + e];
          Pl[(row + i) * 168 + col] = f2h_bits(v);
        }
      }
    }
  }
  __syncthreads();  // Pl ready for FC2 reads

  // ---- (c) FC2: Out[64 tok x 512 c] = Pl @ W2t^T (K=160) ------------------
  // Pl LDS-resident, B frags direct from global: no k-loop barriers.
  for (int nc = 0; nc < 4; ++nc) {
    f32x4 a2[2][4] = {};
#pragma unroll
    for (int kc = 0; kc < 5; ++kc) {
      const int k0 = kc * 32;
      half8 bf4[4];
#pragma unroll
      for (int f = 0; f < 4; ++f)
        bf4[f] = *(const half8*)(W2t + (size_t)(nc * 128 + wn * 64 + f * 16 + cl) * 160 + k0 + qf * 8);
      half8 af[2];
#pragma unroll
      for (int f = 0; f < 2; ++f)
        af[f] = *(const half8*)(Pl + (wm * 32 + f * 16 + cl) * 168 + k0 + qf * 8);
#pragma unroll
      for (int i = 0; i < 2; ++i)
#pragma unroll
        for (int j = 0; j < 4; ++j)
          a2[i][j] = __builtin_amdgcn_mfma_f32_16x16x32_f16(af[i], bf4[j], a2[i][j], 0, 0, 0);
    }
    // transpose + store: single phase (all 4 waves write disjoint (c,trow))
    __syncthreads();  // WAR vs previous nc's ys reads
#pragma unroll
    for (int nf = 0; nf < 4; ++nf) {
      const int c = wn * 64 + nf * 16 + cl;
#pragma unroll
      for (int mf = 0; mf < 2; ++mf) {
        const int trow = wm * 32 + mf * 16 + rq * 4;
#pragma unroll
        for (int i = 0; i < 4; ++i) ys[c * 68 + trow + i] = a2[mf][nf][i];
      }
    }
    __syncthreads();
#pragma unroll
    for (int pass = 0; pass < 8; ++pass) {
      const int c = pass * 16 + (tid >> 4);
      const int f4 = tid & 15;
      float4 v = *(const float4*)&ys[c * 68 + f4 * 4];
      *(float4*)&Out[((size_t)(bi * 512 + nc * 128 + c)) * 4096 + n0 + f4 * 4] = v;
    }
  }
}

// ---------------------------------------------------------------------------
extern "C" void kernel_launch(void* const* d_in, const int* in_sizes, int n_in,
                              void* d_out, int out_size, void* d_ws, size_t ws_size,
                              hipStream_t stream) {
  const float* x     = (const float*)d_in[0];
  const float* wg1   = (const float*)d_in[1];
  const float* bg1   = (const float*)d_in[2];
  const float* gamma = (const float*)d_in[3];
  const float* beta  = (const float*)d_in[4];
  const float* wg2   = (const float*)d_in[5];
  const float* bg2   = (const float*)d_in[6];
  const float* w1    = (const float*)d_in[7];
  const float* b1    = (const float*)d_in[8];
  const float* w2    = (const float*)d_in[9];
  const float* b2    = (const float*)d_in[10];
  float* out = (float*)d_out;

  // Workspace layout (bytes):
  char* ws = (char*)d_ws;
  float*    h     = (float*)ws;                          // 67108864
  ushort_t* Whi   = (ushort_t*)(ws + 67108864);          // 524288
  ushort_t* Wlo   = (ushort_t*)(ws + 67633152);          // 524288
  ushort_t* W1t   = (ushort_t*)(ws + 68157440);          // 131072
  ushort_t* W2t   = (ushort_t*)(ws + 68288512);          // 163840
  float*    stats = (float*)(ws + 68452352);             // 4096
  float*    usage = (float*)(ws + 68456448);             // 32
  uint_t*   done  = (uint_t*)(ws + 68456480);            // 4

  prep<<<1024, 256, 0, stream>>>(wg1, w1, w2, b2, Whi, Wlo, W1t, W2t, stats,
                                 usage, done);
  k1_mfma<<<1024, 256, 0, stream>>>(x, Whi, Wlo, bg1, h, stats);
  k5_fused<<<512, 256, 0, stream>>>(x, W1t, W2t, b1, h, stats, gamma, beta,
                                    wg2, bg2, usage, done, out);
}

// Round 6
// 241.434 us; speedup vs baseline: 1.1057x; 1.1057x over previous
//
#include <hip/hip_runtime.h>

// Problem constants: B=8, N=4096, DIM=C=512, E=8, K=2, H=16, T=B*N=32768
#define T_TOK 32768
#define C_DIM 512
#define N_SEQ 4096

typedef unsigned short ushort_t;
typedef unsigned int uint_t;
typedef __attribute__((ext_vector_type(8))) _Float16 half8;
typedef __attribute__((ext_vector_type(4))) float f32x4;

static __device__ __forceinline__ ushort_t f2h_bits(float f) {
  _Float16 h = (_Float16)f;
  return __builtin_bit_cast(ushort_t, h);
}
static __device__ __forceinline__ float h_bits2f(ushort_t u) {
  return (float)__builtin_bit_cast(_Float16, u);
}

// LDS tile: R rows x 32 f16 (64B rows), stored in 16B slots with XOR swizzle
// slot p holds logical (r = p>>2, q = (p&3) ^ ((r>>1)&3)). Fragment read for
// (row r, k-quarter q) -> ushort off r*32 + (q ^ ((r>>1)&3))*8 => 2-way (free)
// bank aliasing on ds_read_b128 instead of 8-way.
static __device__ __forceinline__ half8 frag_ld(const ushort_t* base, int r, int q) {
  const int off = r * 32 + ((q ^ ((r >> 1) & 3)) * 8);  // in ushorts
  return *(const half8*)(base + off);
}

#define GLOAD_LDS(gptr, lptr)                                                  \
  __builtin_amdgcn_global_load_lds(                                            \
      (const __attribute__((address_space(1))) uint_t*)(gptr),                 \
      (__attribute__((address_space(3))) uint_t*)(lptr), 16, 0, 0)

// ---------------------------------------------------------------------------
// prep (weights-only, grid 1024): wg1 -> hi/lo, w1 -> W1t, w2+b2 -> W2t;
// block 1023 zeroes stats+usage+done.
// ---------------------------------------------------------------------------
__global__ __launch_bounds__(256) void prep(
    const float* __restrict__ wg1, const float* __restrict__ w1,
    const float* __restrict__ w2, const float* __restrict__ b2,
    ushort_t* __restrict__ Whi, ushort_t* __restrict__ Wlo,
    ushort_t* __restrict__ W1t, ushort_t* __restrict__ W2t,
    float* __restrict__ stats, float* __restrict__ usage,
    uint_t* __restrict__ done) {
  const int idx = blockIdx.x * 256 + threadIdx.x;  // 0..262143
  {
    const float v = wg1[idx];
    const ushort_t h = f2h_bits(v);
    Whi[idx] = h;
    Wlo[idx] = f2h_bits(v - h_bits2f(h));
  }
  if (idx < 65536) {
    const int eh = idx >> 9, c = idx & 511;
    const int e = eh >> 4, hh = eh & 15;
    W1t[idx] = f2h_bits(w1[((size_t)e * 512 + c) * 16 + hh]);
  }
  if (idx < 81920) {
    const int c = idx / 160, k = idx - c * 160;
    float v = 0.f;
    if (k < 128) {
      const int e = k >> 4, hh = k & 15;
      v = w2[((size_t)e * 16 + hh) * 512 + c];
    } else if (k < 136) {
      v = b2[(size_t)(k - 128) * 512 + c];
    }
    W2t[c * 160 + k] = f2h_bits(v);
  }
  if (blockIdx.x == 1023) {
    float4 z = {0.f, 0.f, 0.f, 0.f};
    *(float4*)&stats[threadIdx.x * 4] = z;  // 1024 floats
    if (threadIdx.x < 8) usage[threadIdx.x] = 0.f;
    if (threadIdx.x == 8) *done = 0u;
  }
}

// ---------------------------------------------------------------------------
// K1: gate GEMM via split-f16 MFMA, h = (xhi+xlo)@(whi+wlo)^T + bg1,
// PLUS FC1 piggyback: each of the 4 n-siblings of an m-strip computes a
// disjoint 32-wide slice (eh0 = n0>>2) of Ph = relu(Xhi @ W1t^T + b1).
// The A-side (ah frags) is already in registers for the gate GEMM, so FC1
// costs only 1 extra B-frag load (W1t 2KB/chunk slice, L2-hot) + 4 MFMA
// per wave per chunk (+8%). This deletes k5's entire FC1 loop and its 67MB
// X re-read.
// R6: staging structure is R4's exact 2-barrier 32KB form (83us measured;
// R5's 64KB 1-barrier dbuf regressed to 93 -- residency beats pipelining).
// ---------------------------------------------------------------------------
__global__ __launch_bounds__(256) void k1_mfma(
    const float* __restrict__ X, const ushort_t* __restrict__ Whi,
    const ushort_t* __restrict__ Wlo, const ushort_t* __restrict__ W1t,
    const float* __restrict__ bg1, const float* __restrict__ b1,
    float* __restrict__ H, float* __restrict__ stats,
    ushort_t* __restrict__ Ph) {
  __shared__ ushort_t sAh[4096], sAl[4096], sBh[4096], sBl[4096];  // 32 KB
  const int tid = threadIdx.x, lane = tid & 63, w = tid >> 6;
  const int wm = w >> 1, wn = w & 1;
  const int b = blockIdx.x;
  const int m0 = ((b & 7) | ((b >> 5) << 3)) * 128;  // b = 32*(m>>3)+8*n+(m&7)
  const int n0 = ((b >> 3) & 3) * 128;
  const int eh0 = n0 >> 2;  // FC1 column slice [eh0, eh0+32)
  const int cl = lane & 15, qf = lane >> 4, rq = lane >> 4;

  // A-slot geometry: thread handles swizzled slots p1=tid, p2=tid+256
  // (slot p = 8 consecutive f16 of row r=p>>2, k-quarter q=(p&3)^((r>>1)&3)).
  const int p1 = tid, p2 = tid + 256;
  const int r1 = p1 >> 2, q1 = (p1 & 3) ^ ((r1 >> 1) & 3);
  const int r2 = p2 >> 2, q2 = (p2 & 3) ^ ((r2 >> 1) & 3);
  const float* xb1 = X + (size_t)(m0 + r1) * 512 + q1 * 8;
  const float* xb2 = X + (size_t)(m0 + r2) * 512 + q2 * 8;

  float4 xr[4];
#define K1_LOADX(kc)                                                           \
  {                                                                            \
    const int kk = (kc) * 32;                                                  \
    xr[0] = *(const float4*)(xb1 + kk);                                        \
    xr[1] = *(const float4*)(xb1 + kk + 4);                                    \
    xr[2] = *(const float4*)(xb2 + kk);                                        \
    xr[3] = *(const float4*)(xb2 + kk + 4);                                    \
  }

  K1_LOADX(0);
  f32x4 acc[4][4] = {};
  f32x4 acc1[4] = {};  // FC1: 4 m-frags x 16 eh cols (wn half of the slice)

  for (int kc = 0; kc < 16; ++kc) {
    const int k0 = kc * 32;
    __syncthreads();  // barrier1: all frag-reads of chunk kc-1 complete
    // B staging (issue first: max overlap before the draining barrier)
#pragma unroll
    for (int j = 0; j < 2; ++j) {
      const int pb = (w * 2 + j) * 64 + lane;
      const int rb = pb >> 2, qb = (pb & 3) ^ ((rb >> 1) & 3);
      GLOAD_LDS(Whi + (size_t)(n0 + rb) * 512 + k0 + qb * 8, sBh + pb * 8);
      GLOAD_LDS(Wlo + (size_t)(n0 + rb) * 512 + k0 + qb * 8, sBl + pb * 8);
    }
    // A conversion + swizzled ds_write (xr loaded during previous compute)
    {
      ushort_t hi[16], lo[16];
      const float* v = (const float*)xr;
#pragma unroll
      for (int j = 0; j < 16; ++j) {
        hi[j] = f2h_bits(v[j]);
        lo[j] = f2h_bits(v[j] - h_bits2f(hi[j]));
      }
      *(uint4*)(sAh + p1 * 8) = *(uint4*)(hi);
      *(uint4*)(sAl + p1 * 8) = *(uint4*)(lo);
      *(uint4*)(sAh + p2 * 8) = *(uint4*)(hi + 8);
      *(uint4*)(sAl + p2 * 8) = *(uint4*)(lo + 8);
    }
    __syncthreads();  // barrier2: drains B gloads (vmcnt) + A ds_writes (lgkm)
    if (kc < 15) K1_LOADX(kc + 1);  // reg-dbuf prefetch, hides under compute

    // FC1 B-frag (W1t rows [eh0+wn*16, +16), L2-hot 2KB slice)
    half8 bf1 = *(const half8*)(W1t + (size_t)(eh0 + wn * 16 + cl) * 512 + k0 + qf * 8);

    half8 ah[4], al[4], bh[4], bl[4];
#pragma unroll
    for (int f = 0; f < 4; ++f) {
      ah[f] = frag_ld(sAh, wm * 64 + f * 16 + cl, qf);
      al[f] = frag_ld(sAl, wm * 64 + f * 16 + cl, qf);
      bh[f] = frag_ld(sBh, wn * 64 + f * 16 + cl, qf);
      bl[f] = frag_ld(sBl, wn * 64 + f * 16 + cl, qf);
    }
#pragma unroll
    for (int i = 0; i < 4; ++i)
#pragma unroll
      for (int j = 0; j < 4; ++j) {
        acc[i][j] = __builtin_amdgcn_mfma_f32_16x16x32_f16(ah[i], bh[j], acc[i][j], 0, 0, 0);
        acc[i][j] = __builtin_amdgcn_mfma_f32_16x16x32_f16(ah[i], bl[j], acc[i][j], 0, 0, 0);
        acc[i][j] = __builtin_amdgcn_mfma_f32_16x16x32_f16(al[i], bh[j], acc[i][j], 0, 0, 0);
      }
#pragma unroll
    for (int i = 0; i < 4; ++i)
      acc1[i] = __builtin_amdgcn_mfma_f32_16x16x32_f16(ah[i], bf1, acc1[i], 0, 0, 0);
  }
#undef K1_LOADX

  // FC1 epilogue: Ph = f16(relu(acc1 + b1)), 128 tok x 32 eh slice
  {
    const int col = eh0 + wn * 16 + cl;
    const float b1v = b1[col];
#pragma unroll
    for (int mf = 0; mf < 4; ++mf) {
      const int row = m0 + wm * 64 + mf * 16 + rq * 4;
#pragma unroll
      for (int i = 0; i < 4; ++i)
        Ph[(size_t)(row + i) * 128 + col] = f2h_bits(fmaxf(acc1[mf][i] + b1v, 0.f));
    }
  }

  float s[4] = {0, 0, 0, 0}, qs[4] = {0, 0, 0, 0};
#pragma unroll
  for (int nf = 0; nf < 4; ++nf) {
    const int col = n0 + wn * 64 + nf * 16 + cl;
    const float bv = bg1[col];
#pragma unroll
    for (int mf = 0; mf < 4; ++mf) {
      const int row = m0 + wm * 64 + mf * 16 + rq * 4;
#pragma unroll
      for (int i = 0; i < 4; ++i) {
        const float v = acc[mf][nf][i] + bv;
        H[(size_t)(row + i) * 512 + col] = v;
        s[nf] += v;
        qs[nf] += v * v;
      }
    }
  }
#pragma unroll
  for (int nf = 0; nf < 4; ++nf) {
    s[nf] += __shfl_xor(s[nf], 16, 64);
    qs[nf] += __shfl_xor(qs[nf], 16, 64);
    s[nf] += __shfl_xor(s[nf], 32, 64);
    qs[nf] += __shfl_xor(qs[nf], 32, 64);
  }
  if (lane < 16) {
#pragma unroll
    for (int nf = 0; nf < 4; ++nf) {
      const int col = n0 + wn * 64 + nf * 16 + cl;
      atomicAdd(&stats[col], s[nf]);
      atomicAdd(&stats[512 + col], qs[nf]);
    }
  }
}

// ---------------------------------------------------------------------------
// K5 (fused gate+FC2), 64 tokens/block, grid 512 (~62KB LDS, 2 blocks/CU):
//   (a) BN finalize (recomputed) + gating top-2/softmax -> wtab + P ext cols
//   (b) Pl build: Ph (prefetched to regs at kernel start, latency hidden
//       under BN+gating) * gate weight -> Pl f16 [64][168] LDS. The FC1
//       loop is GONE (computed in k1); k5 no longer reads X at all.
//   (c) FC2 MFMA (Pl @ W2t^T, K=160 incl b2 cols): Pl LDS-resident, B
//       direct-to-register -> zero k-loop barriers.
//   lb_loss by last-finisher ticket on `done` (512 blocks -> ticket 511).
// Pl width 168: A-frag stride 336B -> 2-way (free) LDS bank aliasing.
// NOTE uint4 = 8 f16 elements: ext-col zeroing [128,160) = 4 chunks of 8.
// ---------------------------------------------------------------------------
__global__ __launch_bounds__(256) void k5_fused(
    const ushort_t* __restrict__ Ph, const ushort_t* __restrict__ W2t,
    const float* __restrict__ H, const float* __restrict__ stats,
    const float* __restrict__ gamma, const float* __restrict__ beta,
    const float* __restrict__ wg2, const float* __restrict__ bg2,
    float* __restrict__ usage, uint_t* __restrict__ done,
    float* __restrict__ Out) {
  __shared__ ushort_t Pl[64 * 168];     // 21.5 KB
  __shared__ float wtab[64 * 8];        // 2 KB
  __shared__ float ys[128 * 68];        // 34.8 KB
  __shared__ float scsh_l[1024];        // 4 KB
  __shared__ float lus[8];

  const int tid = threadIdx.x, lane = tid & 63, w = tid >> 6;
  const int wm = w >> 1, wn = w & 1;
  const int t0 = blockIdx.x * 64;
  const int bi = t0 >> 12, n0 = t0 & 4095;
  const int cl = lane & 15, qf = lane >> 4, rq = lane >> 4;

  // Ph prefetch: thread owns row prow, cols [pc0, pc0+32). Issued NOW so
  // HBM/L2 latency hides under the whole BN+gating phase.
  const int prow = tid >> 2, pc0 = (tid & 3) * 32;
  const ushort_t* phb = Ph + (size_t)(t0 + prow) * 128 + pc0;
  half8 ph0 = *(const half8*)(phb);
  half8 ph1 = *(const half8*)(phb + 8);
  half8 ph2 = *(const half8*)(phb + 16);
  half8 ph3 = *(const half8*)(phb + 24);

  // ---- init: zero wtab, P ext cols [128,160); BN scale/shift --------------
  if (tid < 8) lus[tid] = 0.f;
  wtab[tid] = 0.f;
  wtab[tid + 256] = 0.f;
  {
    uint4 z = {0, 0, 0, 0};
    const int row = tid >> 2, hf = tid & 3;
    *(uint4*)&Pl[row * 168 + 128 + hf * 8] = z;  // cols 128..159
  }
#pragma unroll
  for (int rep = 0; rep < 2; ++rep) {
    const int c = tid + rep * 256;
    const double mu = (double)stats[c] * (1.0 / (double)T_TOK);
    const double var = (double)stats[512 + c] * (1.0 / (double)T_TOK) - mu * mu;
    const double rstd = 1.0 / sqrt(var + 1e-5);
    const float scv = (float)((double)gamma[c] * rstd);
    scsh_l[c] = scv;
    scsh_l[512 + c] = beta[c] - (float)mu * scv;
  }
  __syncthreads();

  // ---- (a) gating: 4 waves x 16 tokens ------------------------------------
  {
    const int cb = lane * 8;
    float sc[8], sh[8];
#pragma unroll
    for (int i = 0; i < 8; ++i) {
      sc[i] = scsh_l[cb + i];
      sh[i] = scsh_l[512 + cb + i];
    }
    float wg[8][8];
#pragma unroll
    for (int e = 0; e < 8; ++e)
#pragma unroll
      for (int i = 0; i < 8; ++i) wg[e][i] = wg2[e * C_DIM + cb + i];
    float bg[8];
#pragma unroll
    for (int e = 0; e < 8; ++e) bg[e] = bg2[e];

#pragma unroll 2
    for (int it = 0; it < 16; ++it) {
      const int tl = w * 16 + it;
      const float* hr = H + (size_t)(t0 + tl) * C_DIM + cb;
      float4 h0 = *(const float4*)hr;
      float4 h1 = *(const float4*)(hr + 4);
      float y[8] = {h0.x, h0.y, h0.z, h0.w, h1.x, h1.y, h1.z, h1.w};
#pragma unroll
      for (int i = 0; i < 8; ++i) y[i] = fmaxf(fmaf(y[i], sc[i], sh[i]), 0.f);

      float lg[8];
#pragma unroll
      for (int e = 0; e < 8; ++e) {
        float sum = 0.f;
#pragma unroll
        for (int i = 0; i < 8; ++i) sum = fmaf(y[i], wg[e][i], sum);
        lg[e] = sum;
      }
#pragma unroll
      for (int d = 1; d < 64; d <<= 1)
#pragma unroll
        for (int e = 0; e < 8; ++e) lg[e] += __shfl_xor(lg[e], d, 64);
#pragma unroll
      for (int e = 0; e < 8; ++e) lg[e] += bg[e];

      float v1 = lg[0]; int i1 = 0;
#pragma unroll
      for (int e = 1; e < 8; ++e)
        if (lg[e] > v1) { v1 = lg[e]; i1 = e; }
      float v2 = -3.4e38f; int i2 = 0;
#pragma unroll
      for (int e = 0; e < 8; ++e)
        if (e != i1 && lg[e] > v2) { v2 = lg[e]; i2 = e; }

      const float p = expf(v2 - v1);
      const float rw = 1.f / (1.f + p);
      const float w0 = rw, w1 = p * rw;

      if (lane == 0) {
        wtab[tl * 8 + i1] = w0;
        wtab[tl * 8 + i2] = w1;
        Pl[tl * 168 + 128 + i1] = f2h_bits(w0);
        Pl[tl * 168 + 128 + i2] = f2h_bits(w1);
        atomicAdd(&lus[i1], w0);
        atomicAdd(&lus[i2], w1);
      }
    }
  }
  __syncthreads();
  if (tid < 8) atomicAdd(&usage[tid], lus[tid]);
  if (tid == 0) {
    __threadfence();
    const uint_t ticket = atomicAdd(done, 1u);
    if (ticket == 511u) {
      float s = 0.f;
#pragma unroll
      for (int e = 0; e < 8; ++e) {
        const float u = atomicAdd(&usage[e], 0.f) * (1.f / (float)T_TOK);
        s += u * u;
      }
      Out[(size_t)16777216] = s * 8.f;
    }
  }

  // ---- (b) Pl build: Ph * gate weight -> Pl f16 ---------------------------
  {
    const int e0 = pc0 >> 4;
    const float gw0 = wtab[prow * 8 + e0];
    const float gw1 = wtab[prow * 8 + e0 + 1];
    ushort_t o[32];
#pragma unroll
    for (int j = 0; j < 8; ++j) {
      o[j]      = f2h_bits((float)ph0[j] * gw0);
      o[8 + j]  = f2h_bits((float)ph1[j] * gw0);
      o[16 + j] = f2h_bits((float)ph2[j] * gw1);
      o[24 + j] = f2h_bits((float)ph3[j] * gw1);
    }
    *(uint4*)&Pl[prow * 168 + pc0]      = *(uint4*)(o);
    *(uint4*)&Pl[prow * 168 + pc0 + 8]  = *(uint4*)(o + 8);
    *(uint4*)&Pl[prow * 168 + pc0 + 16] = *(uint4*)(o + 16);
    *(uint4*)&Pl[prow * 168 + pc0 + 24] = *(uint4*)(o + 24);
  }
  __syncthreads();  // Pl ready for FC2 reads

  // ---- (c) FC2: Out[64 tok x 512 c] = Pl @ W2t^T (K=160) ------------------
  // Pl LDS-resident, B frags direct from global: no k-loop barriers.
  for (int nc = 0; nc < 4; ++nc) {
    f32x4 a2[2][4] = {};
#pragma unroll
    for (int kc = 0; kc < 5; ++kc) {
      const int k0 = kc * 32;
      half8 bf4[4];
#pragma unroll
      for (int f = 0; f < 4; ++f)
        bf4[f] = *(const half8*)(W2t + (size_t)(nc * 128 + wn * 64 + f * 16 + cl) * 160 + k0 + qf * 8);
      half8 af[2];
#pragma unroll
      for (int f = 0; f < 2; ++f)
        af[f] = *(const half8*)(Pl + (wm * 32 + f * 16 + cl) * 168 + k0 + qf * 8);
#pragma unroll
      for (int i = 0; i < 2; ++i)
#pragma unroll
        for (int j = 0; j < 4; ++j)
          a2[i][j] = __builtin_amdgcn_mfma_f32_16x16x32_f16(af[i], bf4[j], a2[i][j], 0, 0, 0);
    }
    // transpose + store: single phase (all 4 waves write disjoint (c,trow))
    __syncthreads();  // WAR vs previous nc's ys reads
#pragma unroll
    for (int nf = 0; nf < 4; ++nf) {
      const int c = wn * 64 + nf * 16 + cl;
#pragma unroll
      for (int mf = 0; mf < 2; ++mf) {
        const int trow = wm * 32 + mf * 16 + rq * 4;
#pragma unroll
        for (int i = 0; i < 4; ++i) ys[c * 68 + trow + i] = a2[mf][nf][i];
      }
    }
    __syncthreads();
#pragma unroll
    for (int pass = 0; pass < 8; ++pass) {
      const int c = pass * 16 + (tid >> 4);
      const int f4 = tid & 15;
      float4 v = *(const float4*)&ys[c * 68 + f4 * 4];
      *(float4*)&Out[((size_t)(bi * 512 + nc * 128 + c)) * 4096 + n0 + f4 * 4] = v;
    }
  }
}

// ---------------------------------------------------------------------------
extern "C" void kernel_launch(void* const* d_in, const int* in_sizes, int n_in,
                              void* d_out, int out_size, void* d_ws, size_t ws_size,
                              hipStream_t stream) {
  const float* x     = (const float*)d_in[0];
  const float* wg1   = (const float*)d_in[1];
  const float* bg1   = (const float*)d_in[2];
  const float* gamma = (const float*)d_in[3];
  const float* beta  = (const float*)d_in[4];
  const float* wg2   = (const float*)d_in[5];
  const float* bg2   = (const float*)d_in[6];
  const float* w1    = (const float*)d_in[7];
  const float* b1    = (const float*)d_in[8];
  const float* w2    = (const float*)d_in[9];
  const float* b2    = (const float*)d_in[10];
  float* out = (float*)d_out;

  // Workspace layout (bytes):
  char* ws = (char*)d_ws;
  float*    h     = (float*)ws;                          // 67108864
  ushort_t* Whi   = (ushort_t*)(ws + 67108864);          // 524288
  ushort_t* Wlo   = (ushort_t*)(ws + 67633152);          // 524288
  ushort_t* W1t   = (ushort_t*)(ws + 68157440);          // 131072
  ushort_t* W2t   = (ushort_t*)(ws + 68288512);          // 163840
  float*    stats = (float*)(ws + 68452352);             // 4096
  float*    usage = (float*)(ws + 68456448);             // 32
  uint_t*   done  = (uint_t*)(ws + 68456480);            // 4
  ushort_t* Ph    = (ushort_t*)(ws + 68456512);          // 8388608

  prep<<<1024, 256, 0, stream>>>(wg1, w1, w2, b2, Whi, Wlo, W1t, W2t, stats,
                                 usage, done);
  k1_mfma<<<1024, 256, 0, stream>>>(x, Whi, Wlo, W1t, bg1, b1, h, stats, Ph);
  k5_fused<<<512, 256, 0, stream>>>(Ph, W2t, h, stats, gamma, beta, wg2, bg2,
                                    usage, done, out);
}